// Round 1
// baseline (1511.309 us; speedup 1.0000x reference)
//
#include <hip/hip_runtime.h>
#include <hip/hip_bf16.h>
#include <stdint.h>

#define T_TOK 8192
#define H     1024
#define HF    4096
#define NE    8
#define NPAIR (2 * T_TOK)

typedef __bf16 bf16x8 __attribute__((ext_vector_type(8)));
typedef float  floatx4 __attribute__((ext_vector_type(4)));

typedef const __attribute__((address_space(1))) uint32_t g_u32;
typedef __attribute__((address_space(3))) uint32_t l_u32;

__device__ __forceinline__ void async_ld16(const void* g, void* l) {
  // dest lane address = lds_base + lane*16 (wave-uniform base), per-lane global addr
  __builtin_amdgcn_global_load_lds((g_u32*)g, (l_u32*)l, 16, 0, 0);
}

__device__ __forceinline__ unsigned short f2bf(float f) {
  union { float f; uint32_t u; } v; v.f = f;
  uint32_t r = (v.u + 0x7FFFu + ((v.u >> 16) & 1u)) >> 16;
  return (unsigned short)r;
}

// ---------------- init: zero counts ----------------
__global__ void k_init(int* counts) {
  if (threadIdx.x < NE) counts[threadIdx.x] = 0;
}

// ---------------- zero d_out ----------------
__global__ __launch_bounds__(256) void k_zero(float4* p, int n4) {
  int i = blockIdx.x * 256 + threadIdx.x;
  if (i < n4) p[i] = make_float4(0.f, 0.f, 0.f, 0.f);
}

// ---------------- router: one wave per token ----------------
__global__ __launch_bounds__(256) void k_router(const float* __restrict__ x,
                                                const float* __restrict__ gw,
                                                int* counts, int* topk_e, float* topk_w) {
  int wave = threadIdx.x >> 6, lane = threadIdx.x & 63;
  int t = blockIdx.x * 4 + wave;
  float acc[NE];
#pragma unroll
  for (int e = 0; e < NE; e++) acc[e] = 0.f;
  const float* xr = x + (size_t)t * H;
  for (int k = lane; k < H; k += 64) {
    float xv = xr[k];
    const float* g = gw + (size_t)k * NE;
#pragma unroll
    for (int e = 0; e < NE; e++) acc[e] += xv * g[e];
  }
#pragma unroll
  for (int off = 32; off > 0; off >>= 1) {
#pragma unroll
    for (int e = 0; e < NE; e++) acc[e] += __shfl_xor(acc[e], off, 64);
  }
  if (lane == 0) {
    int e1 = 0;
#pragma unroll
    for (int e = 1; e < NE; e++) if (acc[e] > acc[e1]) e1 = e;
    int e2 = (e1 == 0) ? 1 : 0;
#pragma unroll
    for (int e = 0; e < NE; e++) if (e != e1 && acc[e] > acc[e2]) e2 = e;
    // renormalized top-2 softmax weights: w1 = p1/(p1+p2) = 1/(1+exp(l2-l1))
    float w1 = 1.f / (1.f + expf(acc[e2] - acc[e1]));
    topk_e[2 * t] = e1; topk_e[2 * t + 1] = e2;
    topk_w[2 * t] = w1; topk_w[2 * t + 1] = 1.f - w1;
    atomicAdd(&counts[e1], 1);
    atomicAdd(&counts[e2], 1);
  }
}

// ---------------- scan: offsets + zero cursors ----------------
__global__ void k_scan(const int* counts, int* offsets, int* cursors) {
  if (threadIdx.x == 0) {
    int s = 0;
    for (int e = 0; e < NE; e++) { offsets[e] = s; s += counts[e]; cursors[e] = 0; }
    offsets[NE] = s;
  }
}

// ---------------- fill: slot assignment + gather x -> bf16 packed A ----------------
__global__ __launch_bounds__(256) void k_fill(const float* __restrict__ x,
                                              const int* __restrict__ topk_e,
                                              const float* __restrict__ topk_w,
                                              const int* __restrict__ offsets, int* cursors,
                                              int* row_token, float* row_weight,
                                              unsigned short* __restrict__ A_pack) {
  int wave = threadIdx.x >> 6, lane = threadIdx.x & 63;
  int t = blockIdx.x * 4 + wave;
  int s1 = 0, s2 = 0;
  if (lane == 0) {
    int e1 = topk_e[2 * t], e2 = topk_e[2 * t + 1];
    s1 = offsets[e1] + atomicAdd(&cursors[e1], 1);
    s2 = offsets[e2] + atomicAdd(&cursors[e2], 1);
    row_token[s1] = t; row_token[s2] = t;
    row_weight[s1] = topk_w[2 * t];
    row_weight[s2] = topk_w[2 * t + 1];
  }
  s1 = __shfl(s1, 0, 64);
  s2 = __shfl(s2, 0, 64);
  const float* xr = x + (size_t)t * H;
  unsigned short* d1 = A_pack + (size_t)s1 * H;
  unsigned short* d2 = A_pack + (size_t)s2 * H;
  for (int k = lane * 4; k < H; k += 256) {
    float4 v = *(const float4*)(xr + k);
    ushort4 b;
    b.x = f2bf(v.x); b.y = f2bf(v.y); b.z = f2bf(v.z); b.w = f2bf(v.w);
    *(ushort4*)(d1 + k) = b;
    *(ushort4*)(d2 + k) = b;
  }
}

// ---------------- transpose + cvt: [E][K][N] f32 -> [E][N][K] bf16 ----------------
__global__ __launch_bounds__(256) void k_transpose_cvt(const float* __restrict__ src,
                                                       unsigned short* __restrict__ dst,
                                                       int K, int N) {
  __shared__ unsigned short tile[64][65];
  int e = blockIdx.z;
  int k0 = blockIdx.x * 64, n0 = blockIdx.y * 64;
  const float* S = src + (size_t)e * K * N;
  unsigned short* D = dst + (size_t)e * N * K;
  int tr = threadIdx.x >> 4;
  int tc = (threadIdx.x & 15) * 4;
#pragma unroll
  for (int rr = 0; rr < 64; rr += 16) {
    float4 v = *(const float4*)(S + (size_t)(k0 + tr + rr) * N + n0 + tc);
    tile[tr + rr][tc + 0] = f2bf(v.x);
    tile[tr + rr][tc + 1] = f2bf(v.y);
    tile[tr + rr][tc + 2] = f2bf(v.z);
    tile[tr + rr][tc + 3] = f2bf(v.w);
  }
  __syncthreads();
#pragma unroll
  for (int rr = 0; rr < 64; rr += 16) {
    int i = tr + rr;
    ushort4 o;
    o.x = tile[tc + 0][i]; o.y = tile[tc + 1][i];
    o.z = tile[tc + 2][i]; o.w = tile[tc + 3][i];
    *(ushort4*)(D + (size_t)(n0 + i) * K + k0 + tc) = o;
  }
}

// ---------------- GEMM: 128x128 tile, BK=32, 4 waves, mfma_f32_16x16x32_bf16 ----------------
// A: bf16 [rows][KD] packed per-expert segments; BT: bf16 [E][Nd][KD] (k-contiguous)
// SECOND=false: epilogue relu^2 * row_weight -> hidden bf16
// SECOND=true : epilogue atomicAdd into out[token][col]
template <int KD, bool SECOND>
__global__ __launch_bounds__(256) void k_gemm(const unsigned short* __restrict__ A,
                                              const unsigned short* __restrict__ BT,
                                              const int* __restrict__ counts,
                                              const int* __restrict__ offsets,
                                              const float* __restrict__ row_weight,
                                              const int* __restrict__ row_token,
                                              unsigned short* __restrict__ hidden,
                                              float* __restrict__ out, int Nd) {
  int e = blockIdx.z;
  int cnt = counts[e];
  int m0 = blockIdx.y * 128;
  if (m0 >= cnt) return;
  int moff = offsets[e];
  int n0 = blockIdx.x * 128;

  // chunk-major LDS: [q=k/8][row][8 bf16] => linear 16B chunks in DMA lane order
  __shared__ __align__(16) unsigned short As[4 * 128 * 8];
  __shared__ __align__(16) unsigned short Bs[4 * 128 * 8];

  int tid = threadIdx.x, wave = tid >> 6, lane = tid & 63;
  int wm = wave & 1, wn = wave >> 1;

  floatx4 acc[4][4] = {};

  const unsigned short* Ae = A + (size_t)(moff + m0) * KD;
  const unsigned short* Be = BT + (size_t)e * Nd * KD + (size_t)n0 * KD;

  for (int k0 = 0; k0 < KD; k0 += 32) {
    __syncthreads();
#pragma unroll
    for (int s = 0; s < 2; s++) {
      int cgrp = s * 4 + wave;          // 8 chunk-groups of 64 chunks
      int ch = cgrp * 64 + lane;        // my chunk: q = ch>>7, row = ch&127
      int q = ch >> 7, row = ch & 127;
      const unsigned short* ga = Ae + (size_t)row * KD + k0 + q * 8;
      const unsigned short* gb = Be + (size_t)row * KD + k0 + q * 8;
      async_ld16(ga, (void*)(As + cgrp * 512));
      async_ld16(gb, (void*)(Bs + cgrp * 512));
    }
    __syncthreads();

    int q = lane >> 4, l15 = lane & 15;
    bf16x8 aF[4], bF[4];
#pragma unroll
    for (int i = 0; i < 4; i++)
      aF[i] = *(const bf16x8*)&As[(size_t)(q * 128 + wm * 64 + i * 16 + l15) * 8];
#pragma unroll
    for (int j = 0; j < 4; j++)
      bF[j] = *(const bf16x8*)&Bs[(size_t)(q * 128 + wn * 64 + j * 16 + l15) * 8];
#pragma unroll
    for (int i = 0; i < 4; i++)
#pragma unroll
      for (int j = 0; j < 4; j++)
        acc[i][j] = __builtin_amdgcn_mfma_f32_16x16x32_bf16(aF[i], bF[j], acc[i][j], 0, 0, 0);
  }

  int q = lane >> 4, l15 = lane & 15;
#pragma unroll
  for (int i = 0; i < 4; i++) {
#pragma unroll
    for (int r = 0; r < 4; r++) {
      int rl = wm * 64 + i * 16 + q * 4 + r;
      int grow = m0 + rl;
      if (grow < cnt) {
        int p = moff + grow;
        if (!SECOND) {
          float w = row_weight[p];
#pragma unroll
          for (int j = 0; j < 4; j++) {
            int col = n0 + wn * 64 + j * 16 + l15;
            float v = acc[i][j][r];
            v = (v > 0.f) ? v * v * w : 0.f;
            hidden[(size_t)p * HF + col] = f2bf(v);
          }
        } else {
          int tok = row_token[p];
#pragma unroll
          for (int j = 0; j < 4; j++) {
            int col = n0 + wn * 64 + j * 16 + l15;
            atomicAdd(&out[(size_t)tok * H + col], acc[i][j][r]);
          }
        }
      }
    }
  }
}

extern "C" void kernel_launch(void* const* d_in, const int* in_sizes, int n_in,
                              void* d_out, int out_size, void* d_ws, size_t ws_size,
                              hipStream_t stream) {
  const float* x  = (const float*)d_in[0];   // [8192,1024]
  const float* gw = (const float*)d_in[1];   // [1024,8]
  const float* w1 = (const float*)d_in[2];   // [8,1024,4096]
  const float* w2 = (const float*)d_in[3];   // [8,4096,1024]
  float* out = (float*)d_out;

  uint8_t* W = (uint8_t*)d_ws;
  int*   counts    = (int*)(W + 0);
  int*   cursors   = (int*)(W + 64);
  int*   offsets   = (int*)(W + 128);
  int*   topk_e    = (int*)(W + 256);
  float* topk_w    = (float*)(W + 256 + 65536);
  int*   row_token = (int*)(W + 256 + 2 * 65536);
  float* row_weight= (float*)(W + 256 + 3 * 65536);
  size_t MB = 1ull << 20;
  unsigned short* A_pack = (unsigned short*)(W + 1 * MB);                 // (P+128)*1024*2 ~ 32.3MB
  unsigned short* wt1    = (unsigned short*)(W + 35 * MB);                // 64MB
  unsigned short* wt2    = (unsigned short*)(W + 99 * MB);                // 64MB
  unsigned short* hidden = (unsigned short*)(W + 163 * MB);               // (P+128)*4096*2 ~ 129MB
  // total ws use ~292MB

  k_init<<<1, 64, 0, stream>>>(counts);
  k_router<<<T_TOK / 4, 256, 0, stream>>>(x, gw, counts, topk_e, topk_w);
  k_scan<<<1, 64, 0, stream>>>(counts, offsets, cursors);
  k_fill<<<T_TOK / 4, 256, 0, stream>>>(x, topk_e, topk_w, offsets, cursors,
                                        row_token, row_weight, A_pack);
  // w1: K=1024, N=4096 ; w2: K=4096, N=1024
  k_transpose_cvt<<<dim3(H / 64, HF / 64, NE), 256, 0, stream>>>(w1, wt1, H, HF);
  k_transpose_cvt<<<dim3(HF / 64, H / 64, NE), 256, 0, stream>>>(w2, wt2, HF, H);
  k_zero<<<(out_size / 4 + 255) / 256, 256, 0, stream>>>((float4*)out, out_size / 4);

  // GEMM1: [cnt_e,1024] @ [1024,4096] -> relu^2*w -> hidden
  k_gemm<H, false><<<dim3(HF / 128, T_TOK / 128, NE), 256, 0, stream>>>(
      A_pack, wt1, counts, offsets, row_weight, row_token, hidden, out, HF);
  // GEMM2: [cnt_e,4096] @ [4096,1024] -> atomicAdd out
  k_gemm<HF, true><<<dim3(H / 128, T_TOK / 128, NE), 256, 0, stream>>>(
      hidden, wt2, counts, offsets, row_weight, row_token, hidden, out, H);
}

// Round 2
// 1247.938 us; speedup vs baseline: 1.2110x; 1.2110x over previous
//
#include <hip/hip_runtime.h>
#include <hip/hip_bf16.h>
#include <stdint.h>

#define T_TOK 8192
#define H     1024
#define HF    4096
#define NE    8
#define NPAIR (2 * T_TOK)

typedef __bf16 bf16x8 __attribute__((ext_vector_type(8)));
typedef float  floatx4 __attribute__((ext_vector_type(4)));

typedef const __attribute__((address_space(1))) uint32_t g_u32;
typedef __attribute__((address_space(3))) uint32_t l_u32;

__device__ __forceinline__ void async_ld16(const void* g, void* l) {
  // LDS dest = wave-uniform base + lane*16; per-lane global address
  __builtin_amdgcn_global_load_lds((g_u32*)g, (l_u32*)l, 16, 0, 0);
}

__device__ __forceinline__ unsigned short f2bf(float f) {
  union { float f; uint32_t u; } v; v.f = f;
  uint32_t r = (v.u + 0x7FFFu + ((v.u >> 16) & 1u)) >> 16;
  return (unsigned short)r;
}

// ---------------- init: zero counts ----------------
__global__ void k_init(int* counts) {
  if (threadIdx.x < NE) counts[threadIdx.x] = 0;
}

// ---------------- router: one wave per token ----------------
__global__ __launch_bounds__(256) void k_router(const float* __restrict__ x,
                                                const float* __restrict__ gw,
                                                int* counts, int* topk_e, float* topk_w) {
  int wave = threadIdx.x >> 6, lane = threadIdx.x & 63;
  int t = blockIdx.x * 4 + wave;
  float acc[NE];
#pragma unroll
  for (int e = 0; e < NE; e++) acc[e] = 0.f;
  const float* xr = x + (size_t)t * H;
  for (int k = lane; k < H; k += 64) {
    float xv = xr[k];
    const float* g = gw + (size_t)k * NE;
#pragma unroll
    for (int e = 0; e < NE; e++) acc[e] += xv * g[e];
  }
#pragma unroll
  for (int off = 32; off > 0; off >>= 1) {
#pragma unroll
    for (int e = 0; e < NE; e++) acc[e] += __shfl_xor(acc[e], off, 64);
  }
  if (lane == 0) {
    int e1 = 0;
#pragma unroll
    for (int e = 1; e < NE; e++) if (acc[e] > acc[e1]) e1 = e;
    int e2 = (e1 == 0) ? 1 : 0;
#pragma unroll
    for (int e = 0; e < NE; e++) if (e != e1 && acc[e] > acc[e2]) e2 = e;
    // renormalized top-2 softmax weights: w1 = p1/(p1+p2) = 1/(1+exp(l2-l1))
    float w1 = 1.f / (1.f + expf(acc[e2] - acc[e1]));
    topk_e[2 * t] = e1; topk_e[2 * t + 1] = e2;
    topk_w[2 * t] = w1; topk_w[2 * t + 1] = 1.f - w1;
    atomicAdd(&counts[e1], 1);
    atomicAdd(&counts[e2], 1);
  }
}

// ---------------- scan: offsets + zero cursors ----------------
__global__ void k_scan(const int* counts, int* offsets, int* cursors) {
  if (threadIdx.x == 0) {
    int s = 0;
    for (int e = 0; e < NE; e++) { offsets[e] = s; s += counts[e]; cursors[e] = 0; }
    offsets[NE] = s;
  }
}

// ---------------- fill: slot assignment + gather x -> bf16 packed A ----------------
__global__ __launch_bounds__(256) void k_fill(const float* __restrict__ x,
                                              const int* __restrict__ topk_e,
                                              const float* __restrict__ topk_w,
                                              const int* __restrict__ offsets, int* cursors,
                                              int* tok_slot, float* row_weight,
                                              unsigned short* __restrict__ A_pack) {
  int wave = threadIdx.x >> 6, lane = threadIdx.x & 63;
  int t = blockIdx.x * 4 + wave;
  int s1 = 0, s2 = 0;
  if (lane == 0) {
    int e1 = topk_e[2 * t], e2 = topk_e[2 * t + 1];
    s1 = offsets[e1] + atomicAdd(&cursors[e1], 1);
    s2 = offsets[e2] + atomicAdd(&cursors[e2], 1);
    tok_slot[2 * t] = s1; tok_slot[2 * t + 1] = s2;
    row_weight[s1] = topk_w[2 * t];
    row_weight[s2] = topk_w[2 * t + 1];
  }
  s1 = __shfl(s1, 0, 64);
  s2 = __shfl(s2, 0, 64);
  const float* xr = x + (size_t)t * H;
  unsigned short* d1 = A_pack + (size_t)s1 * H;
  unsigned short* d2 = A_pack + (size_t)s2 * H;
  for (int k = lane * 4; k < H; k += 256) {
    float4 v = *(const float4*)(xr + k);
    ushort4 b;
    b.x = f2bf(v.x); b.y = f2bf(v.y); b.z = f2bf(v.z); b.w = f2bf(v.w);
    *(ushort4*)(d1 + k) = b;
    *(ushort4*)(d2 + k) = b;
  }
}

// ---------------- transpose + cvt: [E][K][N] f32 -> [E][N][K] bf16 ----------------
__global__ __launch_bounds__(256) void k_transpose_cvt(const float* __restrict__ src,
                                                       unsigned short* __restrict__ dst,
                                                       int K, int N) {
  __shared__ unsigned short tile[64][65];
  int e = blockIdx.z;
  int k0 = blockIdx.x * 64, n0 = blockIdx.y * 64;
  const float* S = src + (size_t)e * K * N;
  unsigned short* D = dst + (size_t)e * N * K;
  int tr = threadIdx.x >> 4;
  int tc = (threadIdx.x & 15) * 4;
#pragma unroll
  for (int rr = 0; rr < 64; rr += 16) {
    float4 v = *(const float4*)(S + (size_t)(k0 + tr + rr) * N + n0 + tc);
    tile[tr + rr][tc + 0] = f2bf(v.x);
    tile[tr + rr][tc + 1] = f2bf(v.y);
    tile[tr + rr][tc + 2] = f2bf(v.z);
    tile[tr + rr][tc + 3] = f2bf(v.w);
  }
  __syncthreads();
#pragma unroll
  for (int rr = 0; rr < 64; rr += 16) {
    int i = tr + rr;
    ushort4 o;
    o.x = tile[tc + 0][i]; o.y = tile[tc + 1][i];
    o.z = tile[tc + 2][i]; o.w = tile[tc + 3][i];
    *(ushort4*)(D + (size_t)(n0 + i) * K + k0 + tc) = o;
  }
}

// ---------------- GEMM: 128x128 tile, BK=32, 4 waves, mfma_f32_16x16x32_bf16 ----------------
// LDS layout: [row][4 k-quads of 8 bf16], quad XOR-swizzled: lds_q = glob_q ^ (row&3).
// DMA slot s = cgrp*64+lane: row=s>>2 (4-lane groups share a 64B global line -> coalesced).
// SECOND=false: epilogue relu^2 * row_weight -> hidden bf16
// SECOND=true : epilogue -> out_slot[p][col] fp32 (combined later; no atomics)
template <int KD, bool SECOND>
__global__ __launch_bounds__(256) void k_gemm(const unsigned short* __restrict__ A,
                                              const unsigned short* __restrict__ BT,
                                              const int* __restrict__ counts,
                                              const int* __restrict__ offsets,
                                              const float* __restrict__ row_weight,
                                              unsigned short* __restrict__ hidden,
                                              float* __restrict__ out_slot, int Nd) {
  int e = blockIdx.z;
  int cnt = counts[e];
  int m0 = blockIdx.y * 128;
  if (m0 >= cnt) return;
  int moff = offsets[e];
  int n0 = blockIdx.x * 128;

  __shared__ __align__(16) unsigned short As[128 * 32];
  __shared__ __align__(16) unsigned short Bs[128 * 32];

  int tid = threadIdx.x, wave = tid >> 6, lane = tid & 63;
  int wm = wave & 1, wn = wave >> 1;

  floatx4 acc[4][4] = {};

  const unsigned short* Ae = A + (size_t)(moff + m0) * KD;
  const unsigned short* Be = BT + (size_t)e * Nd * KD + (size_t)n0 * KD;

  for (int k0 = 0; k0 < KD; k0 += 32) {
    __syncthreads();
#pragma unroll
    for (int s = 0; s < 2; s++) {
      int cgrp = s * 4 + wave;          // 8 chunk-groups of 64 slots
      int slot = cgrp * 64 + lane;      // LDS 16B-slot index 0..511
      int row = slot >> 2;              // 4 consecutive lanes -> same row
      int qs = slot & 3;                // LDS k-quad
      int qg = qs ^ (row & 3);          // global k-quad (xor swizzle, stays in 64B line)
      const unsigned short* ga = Ae + (size_t)row * KD + k0 + qg * 8;
      const unsigned short* gb = Be + (size_t)row * KD + k0 + qg * 8;
      async_ld16(ga, (void*)(As + cgrp * 512));
      async_ld16(gb, (void*)(Bs + cgrp * 512));
    }
    __syncthreads();

    int q = lane >> 4, l15 = lane & 15;
    bf16x8 aF[4], bF[4];
#pragma unroll
    for (int i = 0; i < 4; i++) {
      int r = wm * 64 + i * 16 + l15;
      aF[i] = *(const bf16x8*)&As[((size_t)r * 4 + (q ^ (r & 3))) * 8];
    }
#pragma unroll
    for (int j = 0; j < 4; j++) {
      int r = wn * 64 + j * 16 + l15;
      bF[j] = *(const bf16x8*)&Bs[((size_t)r * 4 + (q ^ (r & 3))) * 8];
    }
#pragma unroll
    for (int i = 0; i < 4; i++)
#pragma unroll
      for (int j = 0; j < 4; j++)
        acc[i][j] = __builtin_amdgcn_mfma_f32_16x16x32_bf16(aF[i], bF[j], acc[i][j], 0, 0, 0);
  }

  int q = lane >> 4, l15 = lane & 15;
#pragma unroll
  for (int i = 0; i < 4; i++) {
#pragma unroll
    for (int r = 0; r < 4; r++) {
      int rl = wm * 64 + i * 16 + q * 4 + r;
      int grow = m0 + rl;
      if (grow < cnt) {
        int p = moff + grow;
        if (!SECOND) {
          float w = row_weight[p];
#pragma unroll
          for (int j = 0; j < 4; j++) {
            int col = n0 + wn * 64 + j * 16 + l15;
            float v = acc[i][j][r];
            v = (v > 0.f) ? v * v * w : 0.f;
            hidden[(size_t)p * HF + col] = f2bf(v);
          }
        } else {
#pragma unroll
          for (int j = 0; j < 4; j++) {
            int col = n0 + wn * 64 + j * 16 + l15;
            out_slot[(size_t)p * H + col] = acc[i][j][r];
          }
        }
      }
    }
  }
}

// ---------------- combine: out[t] = out_slot[s1] + out_slot[s2] ----------------
__global__ __launch_bounds__(256) void k_combine(const float* __restrict__ out_slot,
                                                 const int* __restrict__ tok_slot,
                                                 float* __restrict__ out) {
  int t = blockIdx.x;
  int s1 = tok_slot[2 * t], s2 = tok_slot[2 * t + 1];
  int c = threadIdx.x * 4;
  float4 a = *(const float4*)(out_slot + (size_t)s1 * H + c);
  float4 b = *(const float4*)(out_slot + (size_t)s2 * H + c);
  float4 o;
  o.x = a.x + b.x; o.y = a.y + b.y; o.z = a.z + b.z; o.w = a.w + b.w;
  *(float4*)(out + (size_t)t * H + c) = o;
}

extern "C" void kernel_launch(void* const* d_in, const int* in_sizes, int n_in,
                              void* d_out, int out_size, void* d_ws, size_t ws_size,
                              hipStream_t stream) {
  const float* x  = (const float*)d_in[0];   // [8192,1024]
  const float* gw = (const float*)d_in[1];   // [1024,8]
  const float* w1 = (const float*)d_in[2];   // [8,1024,4096]
  const float* w2 = (const float*)d_in[3];   // [8,4096,1024]
  float* out = (float*)d_out;

  uint8_t* W = (uint8_t*)d_ws;
  int*   counts    = (int*)(W + 0);
  int*   cursors   = (int*)(W + 64);
  int*   offsets   = (int*)(W + 128);
  int*   topk_e    = (int*)(W + 4096);
  float* topk_w    = (float*)(W + 4096 + 65536);
  int*   tok_slot  = (int*)(W + 4096 + 2 * 65536);
  float* row_weight= (float*)(W + 4096 + 3 * 65536);
  size_t MB = 1ull << 20;
  unsigned short* A_pack = (unsigned short*)(W + 1 * MB);    // ~33.8MB (incl 128-row pad)
  unsigned short* wt1    = (unsigned short*)(W + 35 * MB);   // 64MB
  unsigned short* wt2    = (unsigned short*)(W + 99 * MB);   // 64MB
  unsigned short* hidden = (unsigned short*)(W + 163 * MB);  // ~129.1MB (incl pad) -> 292MB
  float* out_slot = (float*)wt1;  // wt1 is dead after GEMM1; reuse its 64MB for out_slot

  k_init<<<1, 64, 0, stream>>>(counts);
  k_router<<<T_TOK / 4, 256, 0, stream>>>(x, gw, counts, topk_e, topk_w);
  k_scan<<<1, 64, 0, stream>>>(counts, offsets, cursors);
  k_fill<<<T_TOK / 4, 256, 0, stream>>>(x, topk_e, topk_w, offsets, cursors,
                                        tok_slot, row_weight, A_pack);
  // w1: K=1024, N=4096 ; w2: K=4096, N=1024
  k_transpose_cvt<<<dim3(H / 64, HF / 64, NE), 256, 0, stream>>>(w1, wt1, H, HF);
  k_transpose_cvt<<<dim3(HF / 64, H / 64, NE), 256, 0, stream>>>(w2, wt2, HF, H);

  // GEMM1: [cnt_e,1024] @ [1024,4096]^T-layout -> relu^2*w -> hidden (bf16)
  k_gemm<H, false><<<dim3(HF / 128, T_TOK / 128, NE), 256, 0, stream>>>(
      A_pack, wt1, counts, offsets, row_weight, hidden, out_slot, HF);
  // GEMM2: [cnt_e,4096] @ [4096,1024]^T-layout -> out_slot (fp32)
  k_gemm<HF, true><<<dim3(H / 128, T_TOK / 128, NE), 256, 0, stream>>>(
      hidden, wt2, counts, offsets, row_weight, hidden, out_slot, H);
  // combine the two expert contributions per token
  k_combine<<<T_TOK, 256, 0, stream>>>(out_slot, tok_slot, out);
}